// Round 12
// baseline (270.566 us; speedup 1.0000x reference)
//
#include <hip/hip_runtime.h>
#include <hip/hip_bf16.h>
#include <math.h>

#define S_LEN 4096
#define B_SZ  4
#define D_DIM 1024
#define NHEAD 16
#define R_ROWS (S_LEN * B_SZ)   // 16384

#define AS1 __attribute__((address_space(1)))
#define AS3 __attribute__((address_space(3)))

typedef __bf16 bf16_t;
typedef __attribute__((ext_vector_type(8))) __bf16 bf16x8;
typedef __attribute__((ext_vector_type(4))) __bf16 bf16x4;
typedef __attribute__((ext_vector_type(4))) float  f32x4;

#define MFMA16 __builtin_amdgcn_mfma_f32_16x16x32_bf16

__device__ __forceinline__ void gload16(const bf16_t* g, bf16_t* l) {
  __builtin_amdgcn_global_load_lds((const AS1 unsigned int*)g,
                                   (AS3 unsigned int*)l, 16, 0, 0);
}

#define BAR asm volatile("s_barrier" ::: "memory")
#define LGKM0 do { asm volatile("s_waitcnt lgkmcnt(0)" ::: "memory"); \
                   __builtin_amdgcn_sched_barrier(0); } while (0)

// ---------------- stage 0: fp32 -> bf16 converts ----------------
__global__ void k_cvt(const float* __restrict__ src, bf16_t* __restrict__ dst, int n) {
  int i = (blockIdx.x * 256 + threadIdx.x) * 4;
  if (i >= n) return;
  f32x4 v = *(const f32x4*)(src + i);
  bf16x4 o;
  o[0] = (bf16_t)v[0]; o[1] = (bf16_t)v[1]; o[2] = (bf16_t)v[2]; o[3] = (bf16_t)v[3];
  *(bf16x4*)(dst + i) = o;
}
// all four weight matrices in one launch; dst sections contiguous (Wcat q|k|v, WoB).
__global__ void k_cvtw(const float* __restrict__ q, const float* __restrict__ k,
                       const float* __restrict__ v, const float* __restrict__ o,
                       bf16_t* __restrict__ dst) {
  const int sec = blockIdx.x >> 10;
  const int i = ((blockIdx.x & 1023) * 256 + threadIdx.x) * 4;
  const float* s = (sec == 0) ? q : (sec == 1) ? k : (sec == 2) ? v : o;
  f32x4 x = *(const f32x4*)(s + i);
  bf16x4 y;
  y[0] = (bf16_t)x[0]; y[1] = (bf16_t)x[1]; y[2] = (bf16_t)x[2]; y[3] = (bf16_t)x[3];
  *(bf16x4*)(dst + (size_t)sec * 1048576 + i) = y;
}

// =====================================================================
// OCCUPANCY-FIRST counted-vmcnt NT-GEMM core. C[128,128], BK=32, K=1024
// (32 K-tiles, 1 phase each). 512 threads = 8 waves (4M x 2N), 32x64/wave
// (2 m-frags x 4 n-frags), acc = 8 x f32x4 = 32 AGPR -> total regs ~90.
// LDS 48 KB: s*[3][128x32] ring -> 2-3 blocks/CU (vs 1 for all prior
// 8-phase variants). Hypothesis: cross-block overlap (m97 mechanism,
// untested on this shape) hides barrier/drain stalls that intra-block
// scheduling could not (rounds 4-9: 502-660 TF at 1 block/CU).
// Phase t: { rdA(2)+rdB(4) from buf t%3 ; stage tile t+2 into (t+2)%3 ;
//            lgkm0 ; setprio 8 MFMA ; vmcnt(2) ; BAR }.
// Race calculus: stager in phase t passed BAR(t-1) => all waves' reads of
// buf (t+2)%3 (= tile t-1's buffer) completed (lgkm0 precedes BAR) ✓;
// tile t+2's loads drained by phase t+1's vmcnt(2) before t+2 reads ✓.
// vmcnt: outstanding entering phase t = t+1's 2; +2 issued => vmcnt(2)
// leaves t+2's 2 in flight -> NEVER 0 mid-loop (T4). t=30: vmcnt(0).
// Swizzle (T2, rule #21), BK=32: key = (r>>1)&3 — bank-beat analysis:
// start-bank = 16*(r&1) + 4*key covers all 8 positions twice per 16 rows
// -> 2-way (free). (round 5's r&3 key hit half the positions -> 4-way,
// 9.4M conflicts; this fixes it.) Applied to pre-swizzled global source
// (linear gload_lds dest) and to read addrs.
// =====================================================================
__device__ __forceinline__ void gemm_core_occ(
    const bf16_t* __restrict__ A, const bf16_t* __restrict__ B,
    int row0, int col0,
    bf16_t (&sA)[3][4096], bf16_t (&sB)[3][4096], f32x4 (&acc)[2][4])
{
  const int tid  = threadIdx.x;
  const int wave = tid >> 6, lane = tid & 63;
  const int lr = lane & 15, lg = lane >> 4;
  const int wr = wave >> 1, wn = wave & 1;
  const int arow = tid >> 2;                       // staging row 0..127
  const int asw  = (tid & 3) ^ ((arow >> 1) & 3);  // pre-swizzled src chunk

  auto stA = [&](int buf, int k0) {
    gload16(&A[(size_t)(row0 + arow) * D_DIM + k0 + asw * 8],
            &sA[buf][(wave * 64) * 8]);
  };
  auto stB = [&](int buf, int k0) {
    gload16(&B[(size_t)(col0 + arow) * D_DIM + k0 + asw * 8],
            &sB[buf][(wave * 64) * 8]);
  };

  int offA[2], offB[4];
  #pragma unroll
  for (int m = 0; m < 2; ++m) {
    const int r = wr * 32 + m * 16 + lr;
    offA[m] = r * 32 + ((lg ^ ((r >> 1) & 3)) * 8);
  }
  #pragma unroll
  for (int n = 0; n < 4; ++n) {
    const int r = wn * 64 + n * 16 + lr;
    offB[n] = r * 32 + ((lg ^ ((r >> 1) & 3)) * 8);
  }

  #pragma unroll
  for (int m = 0; m < 2; m++)
    #pragma unroll
    for (int n = 0; n < 4; n++)
      #pragma unroll
      for (int r = 0; r < 4; r++) acc[m][n][r] = 0.f;

  // prologue: stage tiles 0 and 1
  stA(0, 0); stB(0, 0); stA(1, 32); stB(1, 32);
  asm volatile("s_waitcnt vmcnt(2)" ::: "memory");   // tile 0 resident
  BAR;

  #pragma unroll 1
  for (int t = 0; t < 32; ++t) {
    const int c = t % 3, cn = (t + 2) % 3;
    bf16x8 af[2], bf[4];
    #pragma unroll
    for (int m = 0; m < 2; ++m) af[m] = *(const bf16x8*)&sA[c][offA[m]];
    #pragma unroll
    for (int n = 0; n < 4; ++n) bf[n] = *(const bf16x8*)&sB[c][offB[n]];
    if (t < 30) { stA(cn, (t + 2) * 32); stB(cn, (t + 2) * 32); }
    LGKM0;
    __builtin_amdgcn_s_setprio(1);
    #pragma unroll
    for (int m = 0; m < 2; ++m)
      #pragma unroll
      for (int n = 0; n < 4; ++n)
        acc[m][n] = MFMA16(af[m], bf[n], acc[m][n], 0, 0, 0);
    __builtin_amdgcn_s_setprio(0);
    if (t < 30)       asm volatile("s_waitcnt vmcnt(2)" ::: "memory");  // t+1 resident
    else if (t == 30) asm volatile("s_waitcnt vmcnt(0)" ::: "memory");  // tile 31 resident
    BAR;
  }
}

// ---------------- stage 1: fused QKV projection ----------------
// C[16384, 3072] = h @ Wcat^T. grid (128, 24). by 0..7 q / 8..15 k / 16..23 v.
// Each wave's 64-col group == one head's full norm group.
__global__ __launch_bounds__(512, 4) void k_proj(
    const bf16_t* __restrict__ hB, const bf16_t* __restrict__ Wcat,
    const float* __restrict__ bq, const float* __restrict__ bk, const float* __restrict__ bv,
    bf16_t* __restrict__ outVb, float* __restrict__ outK, float* __restrict__ outQ,
    bf16_t* __restrict__ qBm)
{
  __shared__ bf16_t sA[3][4096];   // 24 KB
  __shared__ bf16_t sB[3][4096];   // 24 KB

  const int tid  = threadIdx.x;
  const int wave = tid >> 6, lane = tid & 63;
  const int lr = lane & 15, lg = lane >> 4;
  const int wr = wave >> 1, wn = wave & 1;
  const int row0 = blockIdx.x * 128;
  const int by   = blockIdx.y;

  f32x4 acc[2][4];
  gemm_core_occ(hB, Wcat, row0, by * 128, sA, sB, acc);

  const int sec = by >> 3;                                // 0=q 1=k 2=v
  const int hc0 = (by & 7) * 128 + wn * 64;               // col base in [0,1024)
  const float* bias = (sec == 0) ? bq : (sec == 1 ? bk : bv);
  float bvv[4];
  #pragma unroll
  for (int n = 0; n < 4; n++) bvv[n] = bias[hc0 + n * 16 + lr];

  #pragma unroll
  for (int m = 0; m < 2; ++m) {
    #pragma unroll
    for (int r = 0; r < 4; ++r) {
      const int gm = row0 + wr * 32 + m * 16 + lg * 4 + r;
      float v[4];
      float ss = 0.f;
      #pragma unroll
      for (int n = 0; n < 4; n++) {
        v[n] = acc[m][n][r] + bvv[n];
        ss += v[n] * v[n];
      }
      if (sec == 2) {
        #pragma unroll
        for (int n = 0; n < 4; n++)
          outVb[(size_t)gm * D_DIM + hc0 + n * 16 + lr] = (bf16_t)v[n];
      } else {
        #pragma unroll
        for (int msk = 1; msk < 16; msk <<= 1) ss += __shfl_xor(ss, msk);
        const float rs = 1.0f / sqrtf(ss);
        if (sec == 0) {
          const size_t qrow = (size_t)(gm & 3) * S_LEN + (gm >> 2);   // batch-major
          #pragma unroll
          for (int n = 0; n < 4; n++) {
            const float qn = v[n] * rs;
            outQ[(size_t)gm * D_DIM + hc0 + n * 16 + lr] = qn;
            qBm[qrow * D_DIM + hc0 + n * 16 + lr] = (bf16_t)qn;
          }
        } else {
          #pragma unroll
          for (int n = 0; n < 4; n++) {
            float kn = v[n] * rs;
            kn = kn > 0.f ? kn : expm1f(kn);
            outK[(size_t)gm * D_DIM + hc0 + n * 16 + lr] = kn;
          }
        }
      }
    }
  }
}

// ---------------- stage 2: A[b,n,v,q] partials = sum_s v*k ----------------
// grid (64 = b*16+n, 8 s-chunks), 256 threads. V is bf16, K is fp32.
__global__ __launch_bounds__(256) void k_state(
    const float* __restrict__ Kf, const bf16_t* __restrict__ Vb,
    float* __restrict__ Apart)
{
  const int bn = blockIdx.x;
  const int ch = blockIdx.y;
  const int b = bn >> 4, n = bn & 15;
  const int tid = threadIdx.x;
  const int ti = tid >> 4, tj = tid & 15;

  __shared__ float sV[32][64];
  __shared__ float sK[32][64];

  float acc[4][4];
  #pragma unroll
  for (int i = 0; i < 4; i++)
    #pragma unroll
    for (int j = 0; j < 4; j++) acc[i][j] = 0.f;

  const int rr = tid >> 3, cc = (tid & 7) * 8;
  for (int s0 = ch * 512; s0 < ch * 512 + 512; s0 += 32) {
    const size_t g = (size_t)((s0 + rr) * B_SZ + b) * D_DIM + n * 64 + cc;
    bf16x8 v8 = *(const bf16x8*)&Vb[g];
    #pragma unroll
    for (int e = 0; e < 8; e++) sV[rr][cc + e] = (float)v8[e];
    *(f32x4*)&sK[rr][cc]     = *(const f32x4*)&Kf[g];
    *(f32x4*)&sK[rr][cc + 4] = *(const f32x4*)&Kf[g + 4];
    __syncthreads();
    #pragma unroll
    for (int ss = 0; ss < 32; ss++) {
      f32x4 vv = *(const f32x4*)&sV[ss][ti * 4];
      f32x4 kk = *(const f32x4*)&sK[ss][tj * 4];
      #pragma unroll
      for (int i = 0; i < 4; i++)
        #pragma unroll
        for (int j = 0; j < 4; j++)
          acc[i][j] = fmaf(vv[i], kk[j], acc[i][j]);
    }
    __syncthreads();
  }
  float* ap = Apart + ((size_t)ch * 64 + bn) * 4096;
  #pragma unroll
  for (int i = 0; i < 4; i++)
    #pragma unroll
    for (int j = 0; j < 4; j++)
      ap[(ti * 4 + i) * 64 + tj * 4 + j] = acc[i][j];
}

// ---------------- stage 3: Ct[b][d', n*64+dq] = sum_dv Wo[d',n*64+dv]*A[b,n,dv,dq] ----------------
__global__ __launch_bounds__(256) void k_combine(
    const float* __restrict__ Apart, const bf16_t* __restrict__ WoB,
    bf16_t* __restrict__ Ct)
{
  const int bn = blockIdx.x;
  const int dp = blockIdx.y;
  const int b = bn >> 4, n = bn & 15;
  const int tid = threadIdx.x;
  const int ti = tid >> 4, tj = tid & 15;

  __shared__ float sAm[64][65];
  __shared__ float sW[64][65];

  #pragma unroll
  for (int p = 0; p < 16; p++) {
    const int idx = tid + p * 256;
    float s = 0.f;
    #pragma unroll
    for (int c2 = 0; c2 < 8; c2++)
      s += Apart[((size_t)c2 * 64 + bn) * 4096 + idx];
    sAm[idx >> 6][idx & 63] = s;
  }
  {
    const int r = tid >> 2, cv = (tid & 3) * 16;
    bf16x8 w0 = *(const bf16x8*)&WoB[(size_t)(dp * 64 + r) * D_DIM + n * 64 + cv];
    bf16x8 w1 = *(const bf16x8*)&WoB[(size_t)(dp * 64 + r) * D_DIM + n * 64 + cv + 8];
    #pragma unroll
    for (int e = 0; e < 8; e++) {
      sW[r][cv + e]     = (float)w0[e];
      sW[r][cv + 8 + e] = (float)w1[e];
    }
  }
  __syncthreads();

  float acc[4][4];
  #pragma unroll
  for (int i = 0; i < 4; i++)
    #pragma unroll
    for (int j = 0; j < 4; j++) acc[i][j] = 0.f;

  for (int dv = 0; dv < 64; dv++) {
    float w[4], a[4];
    #pragma unroll
    for (int i = 0; i < 4; i++) w[i] = sW[ti * 4 + i][dv];
    #pragma unroll
    for (int j = 0; j < 4; j++) a[j] = sAm[dv][tj * 4 + j];
    #pragma unroll
    for (int i = 0; i < 4; i++)
      #pragma unroll
      for (int j = 0; j < 4; j++)
        acc[i][j] = fmaf(w[i], a[j], acc[i][j]);
  }
  #pragma unroll
  for (int i = 0; i < 4; i++)
    #pragma unroll
    for (int j = 0; j < 4; j++)
      Ct[((size_t)b * D_DIM + dp * 64 + ti * 4 + i) * D_DIM + n * 64 + tj * 4 + j] =
          (bf16_t)acc[i][j];
}

// ---------------- stage 4: out[s*4+b, d'] = qBm[b] @ Ct_b^T + bo ----------------
// grid (32, 8, 4), 512 threads.
__global__ __launch_bounds__(512, 4) void k_final(
    const bf16_t* __restrict__ qBm, const bf16_t* __restrict__ Ct,
    const float* __restrict__ bo, float* __restrict__ outO)
{
  __shared__ bf16_t sA[3][4096];
  __shared__ bf16_t sB[3][4096];

  const int tid  = threadIdx.x;
  const int wave = tid >> 6, lane = tid & 63;
  const int lr = lane & 15, lg = lane >> 4;
  const int wr = wave >> 1, wn = wave & 1;
  const int b    = blockIdx.z;
  const int row0 = blockIdx.x * 128;
  const int col0 = blockIdx.y * 128;

  f32x4 acc[2][4];
  gemm_core_occ(qBm + (size_t)b * S_LEN * D_DIM, Ct + (size_t)b * D_DIM * D_DIM,
                row0, col0, sA, sB, acc);

  #pragma unroll
  for (int m = 0; m < 2; ++m) {
    #pragma unroll
    for (int r = 0; r < 4; ++r) {
      const int gs = row0 + wr * 32 + m * 16 + lg * 4 + r;
      #pragma unroll
      for (int n = 0; n < 4; n++) {
        const int col = col0 + wn * 64 + n * 16 + lr;
        outO[((size_t)gs * B_SZ + b) * D_DIM + col] = acc[m][n][r] + bo[col];
      }
    }
  }
}

extern "C" void kernel_launch(void* const* d_in, const int* in_sizes, int n_in,
                              void* d_out, int out_size, void* d_ws, size_t ws_size,
                              hipStream_t stream) {
  (void)in_sizes; (void)n_in; (void)out_size; (void)ws_size;
  const float* h  = (const float*)d_in[0];
  const float* Wq = (const float*)d_in[1];
  const float* bq = (const float*)d_in[2];
  const float* Wk = (const float*)d_in[3];
  const float* bk = (const float*)d_in[4];
  const float* Wv = (const float*)d_in[5];
  const float* bv = (const float*)d_in[6];
  const float* Wo = (const float*)d_in[7];
  const float* bo = (const float*)d_in[8];

  float* out0 = (float*)d_out;                       // final out
  float* outK = out0 + (size_t)R_ROWS * D_DIM;       // k
  float* outQ = outK + (size_t)R_ROWS * D_DIM;       // q
  bf16_t* vB  = (bf16_t*)d_out;                      // V (bf16) parked in out0's space

  char* ws = (char*)d_ws;
  bf16_t* hB    = (bf16_t*)ws;                                 // 32 MB (dead after proj)
  bf16_t* Ct    = (bf16_t*)ws;                                 // 8 MB, reuses hB space
  bf16_t* Wcat  = (bf16_t*)(ws + 33554432);                    // 6 MB: Wq|Wk|Wv rows
  bf16_t* WoB   = (bf16_t*)(ws + 33554432 + 6291456);          // 2 MB (contiguous after Wcat)
  float*  Apart = (float*)(ws + 41943040);                     // 8 MB
  bf16_t* qBm   = (bf16_t*)(ws + 50331648);                    // 32 MB, batch-major q

  const int nH = R_ROWS * D_DIM;   // 16777216
  k_cvt<<<nH / 1024, 256, 0, stream>>>(h, hB, nH);
  k_cvtw<<<4096, 256, 0, stream>>>(Wq, Wk, Wv, Wo, Wcat);   // fills Wcat+WoB

  k_proj<<<dim3(128, 24), 512, 0, stream>>>(hB, Wcat, bq, bk, bv,
                                            vB, outK, outQ, qBm);
  k_state<<<dim3(64, 8), 256, 0, stream>>>(outK, vB, Apart);
  k_combine<<<dim3(64, 16), 256, 0, stream>>>(Apart, WoB, Ct);
  k_final<<<dim3(S_LEN / 128, D_DIM / 128, B_SZ), 512, 0, stream>>>(qBm, Ct, bo, out0);
}

// Round 13
// 239.337 us; speedup vs baseline: 1.1305x; 1.1305x over previous
//
#include <hip/hip_runtime.h>
#include <hip/hip_bf16.h>
#include <math.h>

#define S_LEN 4096
#define B_SZ  4
#define D_DIM 1024
#define NHEAD 16
#define R_ROWS (S_LEN * B_SZ)   // 16384

#define AS1 __attribute__((address_space(1)))
#define AS3 __attribute__((address_space(3)))

typedef __bf16 bf16_t;
typedef __attribute__((ext_vector_type(8))) __bf16 bf16x8;
typedef __attribute__((ext_vector_type(4))) __bf16 bf16x4;
typedef __attribute__((ext_vector_type(4))) float  f32x4;

#define MFMA16 __builtin_amdgcn_mfma_f32_16x16x32_bf16

__device__ __forceinline__ void gload16(const bf16_t* g, bf16_t* l) {
  __builtin_amdgcn_global_load_lds((const AS1 unsigned int*)g,
                                   (AS3 unsigned int*)l, 16, 0, 0);
}

#define BAR asm volatile("s_barrier" ::: "memory")

// read 4 m-frags x 2 kk from an A-half base. PLAIN loads: the compiler
// inserts precise counted lgkmcnt(N) before each dependent MFMA (G7/m97),
// so the first MFMA starts when ITS operands land — no full drain.
#define RD_A(dst, ap, mlo) \
  _Pragma("unroll") for (int mm = 0; mm < 4; ++mm) \
    _Pragma("unroll") for (int kx = 0; kx < 2; ++kx) \
      dst[mm][kx] = *(const bf16x8*)&ap[offA[(mlo) + mm][kx]];
// read 2 n-frags x 2 kk from a B-half base
#define RD_B(dst, bp, nlo) \
  _Pragma("unroll") for (int nn = 0; nn < 2; ++nn) \
    _Pragma("unroll") for (int kx = 0; kx < 2; ++kx) \
      dst[nn][kx] = *(const bf16x8*)&bp[offB[(nlo) + nn][kx]];
// one C-quadrant x K=64: 16 MFMA, setprio-wrapped (T5).
#define QUAD(mb, nb, AF, BF) \
  do { __builtin_amdgcn_s_setprio(1); \
  _Pragma("unroll") for (int kx = 0; kx < 2; ++kx) \
    _Pragma("unroll") for (int mm = 0; mm < 4; ++mm) \
      _Pragma("unroll") for (int nn = 0; nn < 2; ++nn) \
        acc[(mb)+mm][(nb)+nn] = MFMA16(AF[mm][kx], BF[nn][kx], acc[(mb)+mm][(nb)+nn], 0, 0, 0); \
  __builtin_amdgcn_s_setprio(0); } while (0)

// ---------------- stage 0: fp32 -> bf16 convert, single launch ----------------
// blocks 0..8191: h (16.7M elems, 8/thread). blocks 8192..10239: weights
// into contiguous Wcat q|k|v then WoB (512 blocks each).
__global__ void k_cvt_all(const float* __restrict__ h,
                          const float* __restrict__ wq, const float* __restrict__ wk,
                          const float* __restrict__ wv, const float* __restrict__ wo,
                          bf16_t* __restrict__ hB, bf16_t* __restrict__ wDst) {
  const int blk = blockIdx.x;
  const float* src;
  bf16_t* dst;
  size_t i;
  if (blk < 8192) {
    src = h; dst = hB;
    i = ((size_t)blk * 256 + threadIdx.x) * 8;
  } else {
    const int wb = blk - 8192;
    const int sec = wb >> 9;
    src = (sec == 0) ? wq : (sec == 1) ? wk : (sec == 2) ? wv : wo;
    dst = wDst + (size_t)sec * 1048576;
    i = ((size_t)(wb & 511) * 256 + threadIdx.x) * 8;
  }
  f32x4 v0 = *(const f32x4*)(src + i);
  f32x4 v1 = *(const f32x4*)(src + i + 4);
  bf16x8 o;
  o[0] = (bf16_t)v0[0]; o[1] = (bf16_t)v0[1]; o[2] = (bf16_t)v0[2]; o[3] = (bf16_t)v0[3];
  o[4] = (bf16_t)v1[0]; o[5] = (bf16_t)v1[1]; o[6] = (bf16_t)v1[2]; o[7] = (bf16_t)v1[3];
  *(bf16x8*)(dst + i) = o;
}

// =====================================================================
// 8-phase NT-GEMM core, ONE barrier per phase, NO explicit lgkm drain.
// (round-8 verified schedule minus the LGKM0 full-drain: plain ds_reads
// get compiler-precise counted lgkmcnt before each dependent MFMA.)
// C[256,256], BK=64, K=1024 (16 K-tiles, 8 iters x 2). 512 threads =
// 8 waves (2M x 4N), 128x64/wave. LDS 128 KB: s*[buf][half][128x64].
// Stage targets retire >=2 closing barriers before the stage issue.
// Counted waits (T4, never 0 mid-loop): vmcnt(6) end-P4, vmcnt(8) end-P8.
// Volatile-asm barriers order ALL memory ops (reads can't cross phase
// boundaries); vmcnt waits pin staging drains. Race calculus unchanged
// from r8 (verified absmax 0.5 across 4 runs).
// Swizzle (T2, rule #21): 16B-chunk ^= (row&7); pre-swizzled global source,
// linear gload_lds dest, same XOR on reads -> 0 bank conflicts (PMC).
// Grid-locality (r7/r10 measured): DEFAULT dispatch order only.
// =====================================================================
__device__ __forceinline__ void gemm_core_8ph(
    const bf16_t* __restrict__ A, const bf16_t* __restrict__ B,
    int row0, int col0,
    bf16_t (&sA)[2][2][8192], bf16_t (&sB)[2][2][8192], f32x4 (&acc)[8][4])
{
  const int tid  = threadIdx.x;
  const int wave = tid >> 6, lane = tid & 63;
  const int lr = lane & 15, lg = lane >> 4;
  const int wr = wave >> 2, wn = wave & 3;
  const int grow = tid >> 3;                  // staging row in 64-row stripe
  const int gsw  = (tid & 7) ^ (grow & 7);    // pre-swizzled source chunk

  auto stA = [&](int buf, int half, int k0) {
    #pragma unroll
    for (int j = 0; j < 2; ++j)
      gload16(&A[(size_t)(row0 + half * 128 + j * 64 + grow) * D_DIM + k0 + gsw * 8],
              &sA[buf][half][(j * 64 + wave * 8) * 64]);
  };
  auto stB = [&](int buf, int half, int k0) {
    #pragma unroll
    for (int j = 0; j < 2; ++j)
      gload16(&B[(size_t)(col0 + half * 128 + j * 64 + grow) * D_DIM + k0 + gsw * 8],
              &sB[buf][half][(j * 64 + wave * 8) * 64]);
  };

  // swizzled read offsets (bf16 elems) within a [128][64] half
  int offA[8][2], offB[4][2];
  #pragma unroll
  for (int m = 0; m < 8; ++m) {
    const int r = m * 16 + lr;
    #pragma unroll
    for (int kx = 0; kx < 2; ++kx)
      offA[m][kx] = r * 64 + (((kx << 2) + lg) ^ (r & 7)) * 8;
  }
  #pragma unroll
  for (int n = 0; n < 4; ++n) {
    const int r = (wn & 1) * 64 + n * 16 + lr;
    #pragma unroll
    for (int kx = 0; kx < 2; ++kx)
      offB[n][kx] = r * 64 + (((kx << 2) + lg) ^ (r & 7)) * 8;
  }
  const bf16_t* a0 = &sA[0][wr][0];
  const bf16_t* a1 = &sA[1][wr][0];
  const bf16_t* b0 = &sB[0][wn >> 1][0];
  const bf16_t* b1 = &sB[1][wn >> 1][0];

  #pragma unroll
  for (int m = 0; m < 8; m++)
    #pragma unroll
    for (int n = 0; n < 4; n++)
      #pragma unroll
      for (int r = 0; r < 4; r++) acc[m][n][r] = 0.f;

  // prologue: tiles 0 (buf0, k=0) and 1 (buf1, k=64)
  stA(0, 0, 0);  stA(0, 1, 0);  stB(0, 0, 0);  stB(0, 1, 0);
  stA(1, 0, 64); stA(1, 1, 64); stB(1, 0, 64); stB(1, 1, 64);
  asm volatile("s_waitcnt vmcnt(8)" ::: "memory");   // buf0 resident
  BAR;

  bf16x8 af03[4][2], af47[4][2], bf01[2][2], bf23[2][2];

  #pragma unroll 1
  for (int i = 0; i < 8; ++i) {
    const bool last = (i == 7);
    const int kn0 = (i + 1) * 128, kn1 = kn0 + 64;

    // ---- tile t0 (buf0) ----
    // P1
    RD_A(af03, a0, 0); RD_B(bf01, b0, 0);
    QUAD(0, 0, af03, bf01); BAR;
    // P2
    RD_A(af47, a0, 4);
    QUAD(4, 0, af47, bf01); BAR;
    // P3  (A.h0 retired at BAR(P1))
    RD_B(bf23, b0, 2);
    if (!last) stA(0, 0, kn0);
    QUAD(0, 2, af03, bf23); BAR;
    // P4  (A.h1 retired BAR(P2); B halves retired BAR(P3))
    if (!last) { stA(0, 1, kn0); stB(0, 0, kn0); }
    QUAD(4, 2, af47, bf23);
    if (!last) asm volatile("s_waitcnt vmcnt(6)" ::: "memory");  // buf1 resident
    else       asm volatile("s_waitcnt vmcnt(0)" ::: "memory");
    BAR;

    // ---- tile t1 (buf1) ----
    // P5
    RD_A(af03, a1, 0); RD_B(bf01, b1, 0);
    if (!last) stB(0, 1, kn0);
    QUAD(0, 0, af03, bf01); BAR;
    // P6
    RD_A(af47, a1, 4);
    QUAD(4, 0, af47, bf01); BAR;
    // P7
    RD_B(bf23, b1, 2);
    if (!last) stA(1, 0, kn1);
    QUAD(0, 2, af03, bf23); BAR;
    // P8
    if (!last) { stA(1, 1, kn1); stB(1, 0, kn1); stB(1, 1, kn1); }
    QUAD(4, 2, af47, bf23);
    if (!last) asm volatile("s_waitcnt vmcnt(8)" ::: "memory");  // buf0 resident
    BAR;
  }
}

// ---------------- stage 1: fused QKV projection ----------------
// C[16384, 3072] = h @ Wcat^T. grid (64, 12). by 0..3 q / 4..7 k / 8..11 v.
// Each wave's 64-col group == one head's full norm group.
__global__ __launch_bounds__(512, 2) void k_proj(
    const bf16_t* __restrict__ hB, const bf16_t* __restrict__ Wcat,
    const float* __restrict__ bq, const float* __restrict__ bk, const float* __restrict__ bv,
    bf16_t* __restrict__ outVb, float* __restrict__ outK, float* __restrict__ outQ,
    bf16_t* __restrict__ qBm)
{
  __shared__ bf16_t sA[2][2][8192];   // 64 KB
  __shared__ bf16_t sB[2][2][8192];   // 64 KB

  const int tid  = threadIdx.x;
  const int wave = tid >> 6, lane = tid & 63;
  const int lr = lane & 15, lg = lane >> 4;
  const int wr = wave >> 2, wn = wave & 3;
  const int row0 = blockIdx.x * 256;
  const int by   = blockIdx.y;

  f32x4 acc[8][4];
  gemm_core_8ph(hB, Wcat, row0, by * 256, sA, sB, acc);

  const int sec = by >> 2;                                // 0=q 1=k 2=v
  const int hc0 = (by & 3) * 256 + wn * 64;               // col base in [0,1024)
  const float* bias = (sec == 0) ? bq : (sec == 1 ? bk : bv);
  float bvv[4];
  #pragma unroll
  for (int n = 0; n < 4; n++) bvv[n] = bias[hc0 + n * 16 + lr];

  #pragma unroll
  for (int m = 0; m < 8; ++m) {
    #pragma unroll
    for (int r = 0; r < 4; ++r) {
      const int gm = row0 + wr * 128 + m * 16 + lg * 4 + r;
      float v[4];
      float ss = 0.f;
      #pragma unroll
      for (int n = 0; n < 4; n++) {
        v[n] = acc[m][n][r] + bvv[n];
        ss += v[n] * v[n];
      }
      if (sec == 2) {
        #pragma unroll
        for (int n = 0; n < 4; n++)
          outVb[(size_t)gm * D_DIM + hc0 + n * 16 + lr] = (bf16_t)v[n];
      } else {
        #pragma unroll
        for (int msk = 1; msk < 16; msk <<= 1) ss += __shfl_xor(ss, msk);
        const float rs = 1.0f / sqrtf(ss);
        if (sec == 0) {
          const size_t qrow = (size_t)(gm & 3) * S_LEN + (gm >> 2);   // batch-major
          #pragma unroll
          for (int n = 0; n < 4; n++) {
            const float qn = v[n] * rs;
            outQ[(size_t)gm * D_DIM + hc0 + n * 16 + lr] = qn;
            qBm[qrow * D_DIM + hc0 + n * 16 + lr] = (bf16_t)qn;
          }
        } else {
          #pragma unroll
          for (int n = 0; n < 4; n++) {
            float kn = v[n] * rs;
            kn = kn > 0.f ? kn : expm1f(kn);
            outK[(size_t)gm * D_DIM + hc0 + n * 16 + lr] = kn;
          }
        }
      }
    }
  }
}

// ---------------- stage 2: A[b,n,v,q] partials = sum_s v*k ----------------
// grid (64 = b*16+n, 8 s-chunks), 256 threads. V is bf16, K is fp32.
__global__ __launch_bounds__(256) void k_state(
    const float* __restrict__ Kf, const bf16_t* __restrict__ Vb,
    float* __restrict__ Apart)
{
  const int bn = blockIdx.x;
  const int ch = blockIdx.y;
  const int b = bn >> 4, n = bn & 15;
  const int tid = threadIdx.x;
  const int ti = tid >> 4, tj = tid & 15;

  __shared__ float sV[32][64];
  __shared__ float sK[32][64];

  float acc[4][4];
  #pragma unroll
  for (int i = 0; i < 4; i++)
    #pragma unroll
    for (int j = 0; j < 4; j++) acc[i][j] = 0.f;

  const int rr = tid >> 3, cc = (tid & 7) * 8;
  for (int s0 = ch * 512; s0 < ch * 512 + 512; s0 += 32) {
    const size_t g = (size_t)((s0 + rr) * B_SZ + b) * D_DIM + n * 64 + cc;
    bf16x8 v8 = *(const bf16x8*)&Vb[g];
    #pragma unroll
    for (int e = 0; e < 8; e++) sV[rr][cc + e] = (float)v8[e];
    *(f32x4*)&sK[rr][cc]     = *(const f32x4*)&Kf[g];
    *(f32x4*)&sK[rr][cc + 4] = *(const f32x4*)&Kf[g + 4];
    __syncthreads();
    #pragma unroll
    for (int ss = 0; ss < 32; ss++) {
      f32x4 vv = *(const f32x4*)&sV[ss][ti * 4];
      f32x4 kk = *(const f32x4*)&sK[ss][tj * 4];
      #pragma unroll
      for (int i = 0; i < 4; i++)
        #pragma unroll
        for (int j = 0; j < 4; j++)
          acc[i][j] = fmaf(vv[i], kk[j], acc[i][j]);
    }
    __syncthreads();
  }
  float* ap = Apart + ((size_t)ch * 64 + bn) * 4096;
  #pragma unroll
  for (int i = 0; i < 4; i++)
    #pragma unroll
    for (int j = 0; j < 4; j++)
      ap[(ti * 4 + i) * 64 + tj * 4 + j] = acc[i][j];
}

// ---------------- stage 3: Ct[b][d', n*64+dq] = sum_dv Wo[d',n*64+dv]*A[b,n,dv,dq] ----------------
__global__ __launch_bounds__(256) void k_combine(
    const float* __restrict__ Apart, const bf16_t* __restrict__ WoB,
    bf16_t* __restrict__ Ct)
{
  const int bn = blockIdx.x;
  const int dp = blockIdx.y;
  const int b = bn >> 4, n = bn & 15;
  const int tid = threadIdx.x;
  const int ti = tid >> 4, tj = tid & 15;

  __shared__ float sAm[64][65];
  __shared__ float sW[64][65];

  #pragma unroll
  for (int p = 0; p < 16; p++) {
    const int idx = tid + p * 256;
    float s = 0.f;
    #pragma unroll
    for (int c2 = 0; c2 < 8; c2++)
      s += Apart[((size_t)c2 * 64 + bn) * 4096 + idx];
    sAm[idx >> 6][idx & 63] = s;
  }
  {
    const int r = tid >> 2, cv = (tid & 3) * 16;
    bf16x8 w0 = *(const bf16x8*)&WoB[(size_t)(dp * 64 + r) * D_DIM + n * 64 + cv];
    bf16x8 w1 = *(const bf16x8*)&WoB[(size_t)(dp * 64 + r) * D_DIM + n * 64 + cv + 8];
    #pragma unroll
    for (int e = 0; e < 8; e++) {
      sW[r][cv + e]     = (float)w0[e];
      sW[r][cv + 8 + e] = (float)w1[e];
    }
  }
  __syncthreads();

  float acc[4][4];
  #pragma unroll
  for (int i = 0; i < 4; i++)
    #pragma unroll
    for (int j = 0; j < 4; j++) acc[i][j] = 0.f;

  for (int dv = 0; dv < 64; dv++) {
    float w[4], a[4];
    #pragma unroll
    for (int i = 0; i < 4; i++) w[i] = sW[ti * 4 + i][dv];
    #pragma unroll
    for (int j = 0; j < 4; j++) a[j] = sAm[dv][tj * 4 + j];
    #pragma unroll
    for (int i = 0; i < 4; i++)
      #pragma unroll
      for (int j = 0; j < 4; j++)
        acc[i][j] = fmaf(w[i], a[j], acc[i][j]);
  }
  #pragma unroll
  for (int i = 0; i < 4; i++)
    #pragma unroll
    for (int j = 0; j < 4; j++)
      Ct[((size_t)b * D_DIM + dp * 64 + ti * 4 + i) * D_DIM + n * 64 + tj * 4 + j] =
          (bf16_t)acc[i][j];
}

// ---------------- stage 4: out[s*4+b, d'] = qBm[b] @ Ct_b^T + bo ----------------
// grid (16, 4, 4), 512 threads.
__global__ __launch_bounds__(512, 2) void k_final(
    const bf16_t* __restrict__ qBm, const bf16_t* __restrict__ Ct,
    const float* __restrict__ bo, float* __restrict__ outO)
{
  __shared__ bf16_t sA[2][2][8192];
  __shared__ bf16_t sB[2][2][8192];

  const int tid  = threadIdx.x;
  const int wave = tid >> 6, lane = tid & 63;
  const int lr = lane & 15, lg = lane >> 4;
  const int wr = wave >> 2, wn = wave & 3;
  const int b    = blockIdx.z;
  const int row0 = blockIdx.x * 256;
  const int col0 = blockIdx.y * 256;

  f32x4 acc[8][4];
  gemm_core_8ph(qBm + (size_t)b * S_LEN * D_DIM, Ct + (size_t)b * D_DIM * D_DIM,
                row0, col0, sA, sB, acc);

  #pragma unroll
  for (int m = 0; m < 8; ++m) {
    #pragma unroll
    for (int r = 0; r < 4; ++r) {
      const int gs = row0 + wr * 128 + m * 16 + lg * 4 + r;
      #pragma unroll
      for (int n = 0; n < 4; n++) {
        const int col = col0 + wn * 64 + n * 16 + lr;
        outO[((size_t)gs * B_SZ + b) * D_DIM + col] = acc[m][n][r] + bo[col];
      }
    }
  }
}

extern "C" void kernel_launch(void* const* d_in, const int* in_sizes, int n_in,
                              void* d_out, int out_size, void* d_ws, size_t ws_size,
                              hipStream_t stream) {
  (void)in_sizes; (void)n_in; (void)out_size; (void)ws_size;
  const float* h  = (const float*)d_in[0];
  const float* Wq = (const float*)d_in[1];
  const float* bq = (const float*)d_in[2];
  const float* Wk = (const float*)d_in[3];
  const float* bk = (const float*)d_in[4];
  const float* Wv = (const float*)d_in[5];
  const float* bv = (const float*)d_in[6];
  const float* Wo = (const float*)d_in[7];
  const float* bo = (const float*)d_in[8];

  float* out0 = (float*)d_out;                       // final out
  float* outK = out0 + (size_t)R_ROWS * D_DIM;       // k
  float* outQ = outK + (size_t)R_ROWS * D_DIM;       // q
  bf16_t* vB  = (bf16_t*)d_out;                      // V (bf16) parked in out0's space

  char* ws = (char*)d_ws;
  bf16_t* hB    = (bf16_t*)ws;                                 // 32 MB (dead after proj)
  bf16_t* Ct    = (bf16_t*)ws;                                 // 8 MB, reuses hB space
  bf16_t* Wcat  = (bf16_t*)(ws + 33554432);                    // 6 MB: Wq|Wk|Wv rows
  bf16_t* WoB   = (bf16_t*)(ws + 33554432 + 6291456);          // 2 MB (contiguous after Wcat)
  float*  Apart = (float*)(ws + 41943040);                     // 8 MB
  bf16_t* qBm   = (bf16_t*)(ws + 50331648);                    // 32 MB, batch-major q

  k_cvt_all<<<10240, 256, 0, stream>>>(h, Wq, Wk, Wv, Wo, hB, Wcat);

  k_proj<<<dim3(64, 12), 512, 0, stream>>>(hB, Wcat, bq, bk, bv,
                                           vB, outK, outQ, qBm);
  k_state<<<dim3(64, 8), 256, 0, stream>>>(outK, vB, Apart);
  k_combine<<<dim3(64, 16), 256, 0, stream>>>(Apart, WoB, Ct);
  k_final<<<dim3(S_LEN / 256, D_DIM / 256, B_SZ), 512, 0, stream>>>(qBm, Ct, bo, out0);
}